// Round 15
// baseline (201.052 us; speedup 1.0000x reference)
//
#include <hip/hip_runtime.h>

typedef unsigned int u32;
typedef unsigned short u16;

#define NB 16
#define NN 4096
#define IND 192

typedef __attribute__((ext_vector_type(8))) short short8;
typedef __attribute__((ext_vector_type(4))) float f32x4;
#define MFMA16 __builtin_amdgcn_mfma_f32_16x16x32_bf16

__device__ __forceinline__ float bf2f(u16 u) {
  union { u32 i; float f; } c; c.i = ((u32)u) << 16; return c.f;
}
__device__ __forceinline__ float lo16(u32 u) {
  union { u32 i; float f; } c; c.i = u << 16; return c.f;
}
__device__ __forceinline__ float hi16(u32 u) {
  union { u32 i; float f; } c; c.i = u & 0xffff0000u; return c.f;
}
__device__ __forceinline__ u16 f2bf(float f) {
  union { float f; u32 i; } c; c.f = f;
  u32 r = c.i + 0x7fffu + ((c.i >> 16) & 1u);  // RNE
  return (u16)(r >> 16);
}
__device__ __forceinline__ float ldwf(const void* p, int i, int isf) {
  return isf ? ((const float*)p)[i] : bf2f(((const u16*)p)[i]);
}
__device__ __forceinline__ short8 ld_frag8(const u16* p) {
  union { uint4 u; short8 s; } c;
  c.u = *reinterpret_cast<const uint4*>(p);
  return c.s;
}
__device__ __forceinline__ short8 as_short8(uint4 u) {
  union { uint4 u; short8 s; } c; c.u = u; return c.s;
}
__device__ __forceinline__ short8 pack8(const float* v) {
  short8 s;
  #pragma unroll
  for (int e = 0; e < 8; ++e) s[e] = (short)f2bf(v[e]);
  return s;
}
__device__ __forceinline__ float ln64(float y, float g, float be) {
  float s = y, sq = y * y;
  #pragma unroll
  for (int off = 32; off > 0; off >>= 1) {
    s  += __shfl_xor(s, off, 64);
    sq += __shfl_xor(sq, off, 64);
  }
  float mu  = s * 0.015625f;
  float var = sq * 0.015625f - mu * mu;
  return (y - mu) * rsqrtf(var + 1e-5f) * g + be;
}

// ---------------- dtype detect ----------------
__global__ __launch_bounds__(64) void k_detect(const u32* __restrict__ x2,
                                               int* __restrict__ flag) {
  int t = threadIdx.x;
  int bad = 0;
  for (int i = 0; i < 16; ++i) {
    float a = fabsf(lo16(x2[t * 16 + i]));
    if (!(a < 1e4f)) bad = 1;
  }
  int anybad = __any(bad);
  if (t == 0) *flag = anybad ? 1 : 0;   // 1 = fp32 inputs
}

// ---------------- x -> bf16 ----------------
__global__ __launch_bounds__(256) void k_xb(const int* __restrict__ flag,
                                            const void* __restrict__ x,
                                            u16* __restrict__ xb) {
  const int isf = *flag;
  size_t gid = (size_t)blockIdx.x * 256 + threadIdx.x;
  if (isf) {
    const float4* src = (const float4*)x;
    for (size_t i = gid; i < 3145728; i += 1048576) {
      float4 v = src[i];
      ushort4 o;
      o.x = f2bf(v.x); o.y = f2bf(v.y); o.z = f2bf(v.z); o.w = f2bf(v.w);
      ((ushort4*)xb)[i] = o;
    }
  } else {
    const uint4* src = (const uint4*)x;
    for (size_t i = gid; i < 1572864; i += 1048576)
      ((uint4*)xb)[i] = src[i];
  }
}

// ---------------- per-batch column sums of x (fp32 exact) ----------------
__global__ __launch_bounds__(192) void k_xsum(const int* __restrict__ flag,
                                              const void* __restrict__ x,
                                              float* __restrict__ xsum) {
  const int isf = *flag;
  const int t = threadIdx.x;
  const int r0 = blockIdx.x * 256;
  const int b = r0 >> 12;
  float s = 0.f;
  if (isf) {
    const float* xp = (const float*)x;
    for (int r = 0; r < 256; ++r) s += xp[(size_t)(r0 + r) * 192 + t];
  } else {
    const u16* xp = (const u16*)x;
    for (int r = 0; r < 256; ++r) s += bf2f(xp[(size_t)(r0 + r) * 192 + t]);
  }
  atomicAdd(xsum + b * 192 + t, s);
}

// ---------------- build swizzled B operands ----------------
// Bs1:   [ks(6)][nt(16)][l(64)][e(8)]  over [Wq|Wk|Wv|Win] (192x256)
// BsKlo: [ks(6)][nt'(4)][l(64)][e(8)]  Wk lo-part
// Bs2:   [ks(8)][nt(12)][l(64)][e(8)]  over [Wout;Wp] (256x192)
// W1f:   [ks(2)][nt(8)][l(64)][e(8)]   W1 (64x128)
// W2f:   [ks(4)][nt(4)][l(64)][e(8)]   W2 (128x64)
__global__ __launch_bounds__(256) void k_prepw(
    const int* __restrict__ flag,
    const void* Wq, const void* Wk, const void* Wv, const void* Win,
    const void* Wout, const void* Wp, const void* W1, const void* W2,
    const void* bq, const void* bk, const void* bv,
    u16* __restrict__ Bs1, u16* __restrict__ BsKlo, u16* __restrict__ Bs2,
    u16* __restrict__ W1f, u16* __restrict__ W2f, float* __restrict__ bcat)
{
  const int isf = *flag;
  int idx = blockIdx.x * 256 + threadIdx.x;
  if (idx < 49152) {
    int e = idx & 7, l = (idx >> 3) & 63, g = idx >> 9;
    int nt = g & 15, ks = g >> 4;
    int k = ks * 32 + (l >> 4) * 8 + e;
    int n = nt * 16 + (l & 15);
    const void* W = (n < 64) ? Wq : (n < 128) ? Wk : (n < 192) ? Wv : Win;
    Bs1[idx] = f2bf(ldwf(W, k * 64 + (n & 63), isf));
  } else if (idx < 61440) {
    int j = idx - 49152;
    int e = j & 7, l = (j >> 3) & 63, g = j >> 9;
    int ntp = g & 3, ks = g >> 2;
    int k = ks * 32 + (l >> 4) * 8 + e;
    int n = ntp * 16 + (l & 15);
    float wv = ldwf(Wk, k * 64 + n, isf);
    u16 hi = f2bf(wv);
    BsKlo[j] = f2bf(wv - bf2f(hi));
  } else if (idx < 110592) {
    int j = idx - 61440;
    int e = j & 7, l = (j >> 3) & 63, g = j >> 9;
    int nt = g % 12, ks = g / 12;
    int k = ks * 32 + (l >> 4) * 8 + e;
    int n = nt * 16 + (l & 15);
    float v = (k < 64) ? ldwf(Wout, k * 192 + n, isf)
                       : ldwf(Wp, (k - 64) * 192 + n, isf);
    Bs2[j] = f2bf(v);
  } else if (idx < 118784) {
    int j = idx - 110592;
    int e = j & 7, l = (j >> 3) & 63, g = j >> 9;
    int nt = g & 7, ks = g >> 3;
    int k = ks * 32 + (l >> 4) * 8 + e;
    int n = nt * 16 + (l & 15);
    W1f[j] = f2bf(ldwf(W1, k * 128 + n, isf));
  } else if (idx < 126976) {
    int j = idx - 118784;
    int e = j & 7, l = (j >> 3) & 63, g = j >> 9;
    int nt = g & 3, ks = g >> 2;
    int k = ks * 32 + (l >> 4) * 8 + e;
    int n = nt * 16 + (l & 15);
    W2f[j] = f2bf(ldwf(W2, k * 64 + n, isf));
  } else if (idx < 127232) {
    int n = idx - 126976;
    bcat[n] = (n < 64)  ? ldwf(bq, n, isf)
            : (n < 128) ? ldwf(bk, n - 64, isf)
            : (n < 192) ? ldwf(bv, n - 128, isf) : 0.f;
  }
}

// ---------------- GEMM1 v5: r14 inner structure, 4x row-chunked ----------
// 512 blocks x 512 thr (8 waves), 128 rows/block = 4 chunks of 32.
// B-frags hoisted; stats accumulate in registers across chunks; atomics once.
template<bool F32>
__device__ void gemm1_body(const void* __restrict__ x,
                           const u16* __restrict__ Bs1,
                           const u16* __restrict__ BsKlo,
                           const float* __restrict__ bcat,
                           u16* __restrict__ C1, float* __restrict__ stats,
                           float (*xs)[196], float (*Ks)[65], float (*Vs)[65])
{
  const int tid = threadIdx.x;
  const int bbase = blockIdx.x * 128;
  const int b = bbase >> 12;           // 4096 % 128 == 0 -> constant per block
  const int w = tid >> 6, l = tid & 63, lm = l & 15, lk = l >> 4;
  const int nt0 = w * 2;
  const bool isK = (w == 2) || (w == 3);

  // hoisted B-fragments + bias (identical layout to r14)
  short8 bhi[2][6], blo[2][6];
  #pragma unroll
  for (int n2 = 0; n2 < 2; ++n2)
    #pragma unroll
    for (int ks = 0; ks < 6; ++ks) {
      bhi[n2][ks] = ld_frag8(Bs1 + (size_t)((ks * 16 + nt0 + n2) * 64 + l) * 8);
      if (F32 && isK)
        blo[n2][ks] = ld_frag8(BsKlo + (size_t)((ks * 4 + nt0 + n2 - 4) * 64 + l) * 8);
    }
  float bias[2];
  bias[0] = bcat[nt0 * 16 + lm];
  bias[1] = bcat[(nt0 + 1) * 16 + lm];

  // stats register accumulators (across chunks)
  float sa1[2] = {0.f, 0.f}, sa2[2] = {0.f, 0.f}, sa3[2] = {0.f, 0.f};
  float ssk = 0.f, ssv = 0.f;

  for (int ch = 0; ch < 4; ++ch) {
    const int mbase = bbase + ch * 32;

    if constexpr (F32) {
      for (int i = tid; i < 1536; i += 512) {
        int row = i / 48, c4 = i - row * 48;
        float4 v = *((const float4*)x + (size_t)(mbase + row) * 48 + c4);
        *(float4*)&xs[row][c4 * 4] = v;
      }
    }
    __syncthreads();   // xs ready (F32); prior stats reads done before K/V overwrite

    for (int mt = 0; mt < 2; ++mt) {
      short8 ahi[6], alo[6];
      if constexpr (F32) {
        const float* xr = &xs[mt * 16 + lm][0];
        #pragma unroll
        for (int ks = 0; ks < 6; ++ks) {
          float v[8];
          *(float4*)&v[0] = *(const float4*)(xr + ks * 32 + lk * 8);
          *(float4*)&v[4] = *(const float4*)(xr + ks * 32 + lk * 8 + 4);
          short8 h8;
          #pragma unroll
          for (int e = 0; e < 8; ++e) h8[e] = (short)f2bf(v[e]);
          ahi[ks] = h8;
          if (isK) {
            short8 l8;
            #pragma unroll
            for (int e = 0; e < 8; ++e) {
              float r = v[e] - bf2f((u16)h8[e]);
              l8[e] = (short)f2bf(r);
            }
            alo[ks] = l8;
          }
        }
      } else {
        const u16* xg = (const u16*)x + (size_t)(mbase + mt * 16 + lm) * 192 + lk * 8;
        #pragma unroll
        for (int ks = 0; ks < 6; ++ks) ahi[ks] = ld_frag8(xg + ks * 32);
      }
      f32x4 acc[2];
      #pragma unroll
      for (int n2 = 0; n2 < 2; ++n2) {
        f32x4 a = {bias[n2], bias[n2], bias[n2], bias[n2]};
        acc[n2] = a;
      }
      #pragma unroll
      for (int ks = 0; ks < 6; ++ks)
        #pragma unroll
        for (int n2 = 0; n2 < 2; ++n2) {
          acc[n2] = MFMA16(ahi[ks], bhi[n2][ks], acc[n2], 0, 0, 0);
          if (F32 && isK) {
            acc[n2] = MFMA16(ahi[ks], blo[n2][ks], acc[n2], 0, 0, 0);
            acc[n2] = MFMA16(alo[ks], bhi[n2][ks], acc[n2], 0, 0, 0);
            acc[n2] = MFMA16(alo[ks], blo[n2][ks], acc[n2], 0, 0, 0);
          }
        }
      const int rl = mt * 16 + lk * 4;
      if (w < 2) {
        #pragma unroll
        for (int n2 = 0; n2 < 2; ++n2)
          #pragma unroll
          for (int r = 0; r < 4; ++r)
            C1[(size_t)(mbase + rl + r) * 128 + (nt0 + n2) * 16 + lm] = f2bf(acc[n2][r]);
      } else if (isK) {
        #pragma unroll
        for (int n2 = 0; n2 < 2; ++n2)
          #pragma unroll
          for (int r = 0; r < 4; ++r)
            Ks[rl + r][(nt0 + n2 - 4) * 16 + lm] = acc[n2][r];
      } else if (w < 6) {
        #pragma unroll
        for (int n2 = 0; n2 < 2; ++n2)
          #pragma unroll
          for (int r = 0; r < 4; ++r)
            Vs[rl + r][(nt0 + n2 - 8) * 16 + lm] = acc[n2][r];
      } else {
        #pragma unroll
        for (int n2 = 0; n2 < 2; ++n2)
          #pragma unroll
          for (int r = 0; r < 4; ++r)
            C1[(size_t)(mbase + rl + r) * 128 + 64 + (nt0 + n2 - 12) * 16 + lm] = f2bf(acc[n2][r]);
      }
    }
    __syncthreads();   // K/V ready for stats

    #pragma unroll
    for (int it = 0; it < 2; ++it) {
      int item = tid + it * 512;
      int hh = item >> 8, f = (item >> 4) & 15, c = item & 15;
      float a1 = sa1[it], a2 = sa2[it], a3 = sa3[it];
      for (int r = 0; r < 32; ++r) {
        float kv = Ks[r][hh * 16 + f];
        float vv = Vs[r][hh * 16 + c];
        float k2 = kv * kv;
        a1 = fmaf(kv, vv, a1);
        a2 = fmaf(k2, vv, a2);
        a3 = fmaf(k2 * kv, vv, a3);
      }
      sa1[it] = a1; sa2[it] = a2; sa3[it] = a3;
    }
    if (tid < 192) {
      int kk = tid >> 6, hf = tid & 63;
      float s = ssk;
      for (int r = 0; r < 32; ++r) {
        float kv = Ks[r][hf];
        s += (kk == 0) ? kv : (kk == 1) ? kv * kv : kv * kv * kv;
      }
      ssk = s;
    } else if (tid < 256) {
      int hf = tid - 192;
      float s = ssv;
      for (int r = 0; r < 32; ++r) s += Vs[r][hf];
      ssv = s;
    }
  }

  // one round of atomics per block (was 4x)
  float* sb = stats + (size_t)(b * 4) * 832;
  #pragma unroll
  for (int it = 0; it < 2; ++it) {
    int item = tid + it * 512;
    int hh = item >> 8, f = (item >> 4) & 15, c = item & 15;
    float* base = sb + (size_t)hh * 832 + f * 16 + c;
    atomicAdd(base, sa1[it]);
    atomicAdd(base + 256, sa2[it]);
    atomicAdd(base + 512, sa3[it]);
  }
  if (tid < 192) {
    int kk = tid >> 6, hf = tid & 63, h2 = hf >> 4, ff = hf & 15;
    atomicAdd(sb + (size_t)h2 * 832 + 768 + kk * 16 + ff, ssk);
  } else if (tid < 256) {
    int hf = tid - 192, h2 = hf >> 4;
    atomicAdd(sb + (size_t)h2 * 832 + 816 + (hf & 15), ssv);
  }
}

__global__ __launch_bounds__(512, 2) void k_gemm1(
    const int* __restrict__ flag, const void* __restrict__ x,
    const u16* __restrict__ Bs1, const u16* __restrict__ BsKlo,
    const float* __restrict__ bcat,
    u16* __restrict__ C1, float* __restrict__ stats)
{
  __shared__ float xs[32][196];
  __shared__ float Ks[32][65];
  __shared__ float Vs[32][65];
  if (*flag) gemm1_body<true >(x, Bs1, BsKlo, bcat, C1, stats, xs, Ks, Vs);
  else       gemm1_body<false>(x, Bs1, BsKlo, bcat, C1, stats, xs, Ks, Vs);
}

// ---------------- finalize (exact sumN1 via xsum) ----------------
template<bool F32>
__device__ void finalize_body(const float* stats, const void* Pi,
                              const void* Wk, const void* bk,
                              const float* xsum, float* M, float* sn1)
{
  const int bh = blockIdx.x, bb = bh >> 2, h = bh & 3, t = threadIdx.x;
  const float* sb = stats + (size_t)bh * 832;
  float* mb = M + (size_t)bh * 784;
  const float inv6 = 1.0f / 6.0f;

  {
    int f = t >> 4, s = t & 15;
    float p = 0.f;
    for (int i = s * 12; i < s * 12 + 12; ++i)
      p += xsum[bb * 192 + i] * ldwf(Wk, i * 64 + h * 16 + f, F32);
    p += __shfl_xor(p, 1, 64);
    p += __shfl_xor(p, 2, 64);
    p += __shfl_xor(p, 4, 64);
    p += __shfl_xor(p, 8, 64);
    if (s == 0) sn1[f] = p + 4096.0f * ldwf(bk, h * 16 + f, F32);
  }
  __syncthreads();

  {
    const int f = t >> 4, c = t & 15;
    #pragma unroll
    for (int k = 0; k < 3; ++k) {
      float fkv = sb[k * 256 + f * 16 + c];
      float sk  = (k == 0) ? sn1[f] : sb[768 + k * 16 + f];
      float pi  = ldwf(Pi, h * 4 + (k + 1), F32);
      mb[k * 256 + f * 16 + c] = fkv / ((sk + 1e-8f) * 4.0f) * pi * inv6;
    }
  }
  if (t < 16) {
    float sv  = sb[816 + t];
    float pi0 = ldwf(Pi, h * 4 + 0, F32);
    mb[768 + t] = sv / (4096.0f + 1e-8f) * pi0 * inv6;
  }
}

__global__ __launch_bounds__(256) void k_finalize(
    const int* __restrict__ flag, const float* __restrict__ stats,
    const void* __restrict__ Pi, const void* __restrict__ Wk,
    const void* __restrict__ bk, const float* __restrict__ xsum,
    float* __restrict__ M)
{
  __shared__ float sn1[16];
  if (*flag) finalize_body<true >(stats, Pi, Wk, bk, xsum, M, sn1);
  else       finalize_body<false>(stats, Pi, Wk, bk, xsum, M, sn1);
}

// ---------------- mid: MFMA att + LN + MFMA FFN + LN (r14 verbatim) ---------
template<bool F32> __device__ void mid_body(
    const u16* __restrict__ C1, u16* __restrict__ R2,
    const float* __restrict__ Mall,
    const u16* __restrict__ W1f, const u16* __restrict__ W2f,
    const void* __restrict__ b1, const void* __restrict__ b2,
    const void* __restrict__ lng, const void* __restrict__ lnb,
    float (*attL)[72], u16 (*resB)[72], u16 (*hB)[136])
{
  const int tid = threadIdx.x;
  const int w = tid >> 6, l = tid & 63;
  const int lm = l & 15, lk = l >> 4;
  const int n0g = blockIdx.x * 64;
  const int b = n0g >> 12;
  const int n2_0 = n0g & 4095;
  const int h = n2_0 >> 10;
  const int qg0 = (b << 12) + ((n2_0 & 1023) << 2);
  const float* mb = Mall + (size_t)((b << 2) + h) * 784;

  short8 Bhi[2], Blo[2];
  #pragma unroll
  for (int ks = 0; ks < 2; ++ks) {
    float vh[8], vl[8];
    #pragma unroll
    for (int e = 0; e < 8; ++e) {
      int kk = ks * 32 + lk * 8 + e;
      float v = (kk < 16) ? mb[kk * 16 + lm]
              : (kk < 32) ? mb[256 + (kk - 16) * 16 + lm]
              : (kk < 48) ? mb[512 + (kk - 32) * 16 + lm] : 0.f;
      float hi = bf2f(f2bf(v));
      vh[e] = hi; vl[e] = v - hi;
    }
    Bhi[ks] = pack8(vh);
    Blo[ks] = pack8(vl);
  }
  const float c0v = mb[768 + lm];

  #pragma unroll
  for (int mt2 = 0; mt2 < 4; ++mt2) {
    const int mt = w * 4 + mt2;
    uint4 qv = *(const uint4*)(C1 + (size_t)(qg0 + mt * 16 + lm) * 128
                               + h * 16 + (lk & 1) * 8);
    float q[8] = {lo16(qv.x), hi16(qv.x), lo16(qv.y), hi16(qv.y),
                  lo16(qv.z), hi16(qv.z), lo16(qv.w), hi16(qv.w)};
    float q2[8], q3[8];
    #pragma unroll
    for (int e = 0; e < 8; ++e) { q2[e] = q[e] * q[e]; q3[e] = q2[e] * q[e]; }
    short8 a1, a2;
    if (lk < 2) { a1 = as_short8(qv); a2 = pack8(q3); }
    else        { a1 = pack8(q2);     a2 = short8{0,0,0,0,0,0,0,0}; }

    f32x4 acc = {c0v, c0v, c0v, c0v};
    acc = MFMA16(a1, Bhi[0], acc, 0, 0, 0);
    acc = MFMA16(a1, Blo[0], acc, 0, 0, 0);
    acc = MFMA16(a2, Bhi[1], acc, 0, 0, 0);
    acc = MFMA16(a2, Blo[1], acc, 0, 0, 0);

    #pragma unroll
    for (int r = 0; r < 4; ++r) {
      int qr = mt * 16 + lk * 4 + r;
      attL[qr >> 2][(qr & 3) * 16 + lm] = acc[r];
    }
  }

  const float gj = ldwf(lng, l, F32), bj = ldwf(lnb, l, F32);
  #pragma unroll 4
  for (int rr = 0; rr < 16; ++rr) {
    int r = w * 16 + rr;
    float proj = bf2f(C1[(size_t)(n0g + r) * 128 + 64 + l]);
    float y = proj + attL[r][l];
    resB[r][l] = f2bf(ln64(y, gj, bj));
  }

  short8 a0 = *(const short8*)&resB[w * 16 + lm][lk * 8];
  short8 a1f = *(const short8*)&resB[w * 16 + lm][32 + lk * 8];
  f32x4 hacc[8];
  #pragma unroll
  for (int nt = 0; nt < 8; ++nt) {
    float bv = ldwf(b1, nt * 16 + lm, F32);
    f32x4 a = {bv, bv, bv, bv};
    hacc[nt] = a;
  }
  #pragma unroll
  for (int nt = 0; nt < 8; ++nt) {
    short8 w1a = ld_frag8(W1f + (size_t)((0 * 8 + nt) * 64 + l) * 8);
    short8 w1b = ld_frag8(W1f + (size_t)((1 * 8 + nt) * 64 + l) * 8);
    hacc[nt] = MFMA16(a0, w1a, hacc[nt], 0, 0, 0);
    hacc[nt] = MFMA16(a1f, w1b, hacc[nt], 0, 0, 0);
  }
  #pragma unroll
  for (int nt = 0; nt < 8; ++nt)
    #pragma unroll
    for (int r = 0; r < 4; ++r) {
      int row = w * 16 + lk * 4 + r;
      hB[row][nt * 16 + lm] = f2bf(fmaxf(hacc[nt][r], 0.f));
    }

  short8 ha[4];
  #pragma unroll
  for (int ks = 0; ks < 4; ++ks)
    ha[ks] = *(const short8*)&hB[w * 16 + lm][ks * 32 + lk * 8];
  f32x4 oacc[4];
  #pragma unroll
  for (int nt = 0; nt < 4; ++nt) {
    float bv = ldwf(b2, nt * 16 + lm, F32);
    f32x4 a = {bv, bv, bv, bv};
    oacc[nt] = a;
  }
  #pragma unroll
  for (int ks = 0; ks < 4; ++ks)
    #pragma unroll
    for (int nt = 0; nt < 4; ++nt) {
      short8 w2v = ld_frag8(W2f + (size_t)((ks * 4 + nt) * 64 + l) * 8);
      oacc[nt] = MFMA16(ha[ks], w2v, oacc[nt], 0, 0, 0);
    }

  float gcol[4], bcol[4];
  #pragma unroll
  for (int nt = 0; nt < 4; ++nt) {
    gcol[nt] = ldwf(lng, nt * 16 + lm, F32);
    bcol[nt] = ldwf(lnb, nt * 16 + lm, F32);
  }
  #pragma unroll
  for (int r = 0; r < 4; ++r) {
    int row = w * 16 + lk * 4 + r;
    float y[4];
    float s = 0.f, sq = 0.f;
    #pragma unroll
    for (int nt = 0; nt < 4; ++nt) {
      y[nt] = oacc[nt][r] + bf2f(resB[row][nt * 16 + lm]);
      s += y[nt];
      sq = fmaf(y[nt], y[nt], sq);
    }
    #pragma unroll
    for (int off = 8; off > 0; off >>= 1) {
      s  += __shfl_xor(s, off, 64);
      sq += __shfl_xor(sq, off, 64);
    }
    float mu = s * 0.015625f;
    float var = sq * 0.015625f - mu * mu;
    float rs = rsqrtf(var + 1e-5f);
    #pragma unroll
    for (int nt = 0; nt < 4; ++nt) {
      float r2v = (y[nt] - mu) * rs * gcol[nt] + bcol[nt];
      R2[(size_t)(n0g + row) * 64 + nt * 16 + lm] = f2bf(r2v);
    }
  }
}

__global__ __launch_bounds__(256, 2) void k_mid(
    const int* __restrict__ flag, const u16* __restrict__ C1,
    u16* __restrict__ R2, const float* __restrict__ Mall,
    const u16* __restrict__ W1f, const u16* __restrict__ W2f,
    const void* __restrict__ b1, const void* __restrict__ b2,
    const void* __restrict__ lng, const void* __restrict__ lnb)
{
  __shared__ float attL[64][72];
  __shared__ u16 resB[64][72];
  __shared__ u16 hB[64][136];
  if (*flag) mid_body<true >(C1, R2, Mall, W1f, W2f, b1, b2, lng, lnb, attL, resB, hB);
  else       mid_body<false>(C1, R2, Mall, W1f, W2f, b1, b2, lng, lnb, attL, resB, hB);
}

// ---------------- GEMM2: out = [res2|x] @ [Wout;Wp] + bout (r14 verbatim) ---
__global__ __launch_bounds__(256, 2) void k_gemm2(
    const int* __restrict__ flag,
    const u16* __restrict__ R2, const u16* __restrict__ xb,
    const u16* __restrict__ Bs2, const void* __restrict__ bout,
    void* __restrict__ out)
{
  const int isf = *flag;
  const int l = threadIdx.x & 63;
  const int w = threadIdx.x >> 6;
  const int mbase = blockIdx.x * 64;
  const int lm = l & 15, lk = l >> 4;

  short8 bf[8][3];
  #pragma unroll
  for (int ks = 0; ks < 8; ++ks)
    #pragma unroll
    for (int nt = 0; nt < 3; ++nt)
      bf[ks][nt] = ld_frag8(Bs2 + (size_t)((ks * 12 + w * 3 + nt) * 64 + l) * 8);

  float bias[3];
  #pragma unroll
  for (int nt = 0; nt < 3; ++nt) bias[nt] = ldwf(bout, w * 48 + nt * 16 + lm, isf);

  short8 af[8];
  {
    const int row = mbase + lm;
    const u16* rp = R2 + (size_t)row * 64 + lk * 8;
    af[0] = ld_frag8(rp);
    af[1] = ld_frag8(rp + 32);
    const u16* xp = xb + (size_t)row * IND + lk * 8;
    #pragma unroll
    for (int ks = 2; ks < 8; ++ks) af[ks] = ld_frag8(xp + (ks - 2) * 32);
  }

  for (int mt = 0; mt < 4; ++mt) {
    short8 afn[8];
    if (mt < 3) {
      const int row = mbase + (mt + 1) * 16 + lm;
      const u16* rp = R2 + (size_t)row * 64 + lk * 8;
      afn[0] = ld_frag8(rp);
      afn[1] = ld_frag8(rp + 32);
      const u16* xp = xb + (size_t)row * IND + lk * 8;
      #pragma unroll
      for (int ks = 2; ks < 8; ++ks) afn[ks] = ld_frag8(xp + (ks - 2) * 32);
    }
    f32x4 acc[3];
    #pragma unroll
    for (int nt = 0; nt < 3; ++nt) {
      f32x4 a = {bias[nt], bias[nt], bias[nt], bias[nt]};
      acc[nt] = a;
    }
    #pragma unroll
    for (int ks = 0; ks < 8; ++ks)
      #pragma unroll
      for (int nt = 0; nt < 3; ++nt)
        acc[nt] = MFMA16(af[ks], bf[ks][nt], acc[nt], 0, 0, 0);
    const int r0 = mbase + mt * 16 + lk * 4;
    const int c0 = w * 48 + lm;
    if (isf) {
      float* op = (float*)out;
      #pragma unroll
      for (int nt = 0; nt < 3; ++nt)
        #pragma unroll
        for (int r = 0; r < 4; ++r)
          op[(size_t)(r0 + r) * IND + c0 + nt * 16] = acc[nt][r];
    } else {
      u16* op = (u16*)out;
      #pragma unroll
      for (int nt = 0; nt < 3; ++nt)
        #pragma unroll
        for (int r = 0; r < 4; ++r)
          op[(size_t)(r0 + r) * IND + c0 + nt * 16] = f2bf(acc[nt][r]);
    }
    #pragma unroll
    for (int ks = 0; ks < 8; ++ks) af[ks] = afn[ks];
  }
}

extern "C" void kernel_launch(void* const* d_in, const int* in_sizes, int n_in,
                              void* d_out, int out_size, void* d_ws, size_t ws_size,
                              hipStream_t stream)
{
  const void* x   = d_in[0];
  const void* Wq  = d_in[1];
  const void* bq  = d_in[2];
  const void* Wk  = d_in[3];
  const void* bk  = d_in[4];
  const void* Wv  = d_in[5];
  const void* bv  = d_in[6];
  const void* Win = d_in[7];
  const void* Wout= d_in[8];
  const void* bout= d_in[9];
  const void* W1  = d_in[10];
  const void* b1  = d_in[11];
  const void* W2  = d_in[12];
  const void* b2  = d_in[13];
  const void* lng = d_in[14];
  const void* lnb = d_in[15];
  const void* Wp  = d_in[16];
  const void* Pi  = d_in[17];

  u16* xb    = (u16*)d_ws;                  // 12,582,912
  u16* C1    = xb + (size_t)12582912;       // 8,388,608  (Q | proj)
  u16* R2    = C1 + (size_t)8388608;        // 4,194,304  (res2)
  u16* Bs1   = R2 + (size_t)4194304;        // 49,152
  u16* BsKlo = Bs1 + 49152;                 // 12,288
  u16* Bs2   = BsKlo + 12288;               // 49,152
  u16* W1f   = Bs2 + 49152;                 // 8,192
  u16* W2f   = W1f + 8192;                  // 8,192
  float* bcat  = (float*)(W2f + 8192);      // 256
  float* stats = bcat + 256;                // 53,248
  float* xsum  = stats + 53248;             // 3,072
  float* Mc    = xsum + 3072;               // 50,176
  int*   flag  = (int*)(Mc + 50176);

  k_detect<<<1, 64, 0, stream>>>((const u32*)x, flag);
  hipMemsetAsync(stats, 0, (size_t)(53248 + 3072) * sizeof(float), stream);

  k_prepw<<<497, 256, 0, stream>>>(flag, Wq, Wk, Wv, Win, Wout, Wp, W1, W2,
                                   bq, bk, bv, Bs1, BsKlo, Bs2, W1f, W2f, bcat);
  k_xb<<<4096, 256, 0, stream>>>(flag, x, xb);
  k_xsum<<<256, 192, 0, stream>>>(flag, x, xsum);
  k_gemm1<<<512, 512, 0, stream>>>(flag, x, Bs1, BsKlo, bcat, C1, stats);
  k_finalize<<<64, 256, 0, stream>>>(flag, stats, Pi, Wk, bk, xsum, Mc);
  k_mid<<<1024, 256, 0, stream>>>(flag, C1, R2, Mc, W1f, W2f, b1, b2, lng, lnb);
  k_gemm2<<<1024, 256, 0, stream>>>(flag, R2, xb, Bs2, bout, d_out);
}

// Round 17
// 161.998 us; speedup vs baseline: 1.2411x; 1.2411x over previous
//
#include <hip/hip_runtime.h>

typedef unsigned int u32;
typedef unsigned short u16;

#define NB 16
#define NN 4096
#define IND 192

typedef __attribute__((ext_vector_type(8))) short short8;
typedef __attribute__((ext_vector_type(4))) float f32x4;
#define MFMA16 __builtin_amdgcn_mfma_f32_16x16x32_bf16

__device__ __forceinline__ float bf2f(u16 u) {
  union { u32 i; float f; } c; c.i = ((u32)u) << 16; return c.f;
}
__device__ __forceinline__ float lo16(u32 u) {
  union { u32 i; float f; } c; c.i = u << 16; return c.f;
}
__device__ __forceinline__ float hi16(u32 u) {
  union { u32 i; float f; } c; c.i = u & 0xffff0000u; return c.f;
}
__device__ __forceinline__ u16 f2bf(float f) {
  union { float f; u32 i; } c; c.f = f;
  u32 r = c.i + 0x7fffu + ((c.i >> 16) & 1u);  // RNE
  return (u16)(r >> 16);
}
__device__ __forceinline__ float ldwf(const void* p, int i, int isf) {
  return isf ? ((const float*)p)[i] : bf2f(((const u16*)p)[i]);
}
__device__ __forceinline__ short8 ld_frag8(const u16* p) {
  union { uint4 u; short8 s; } c;
  c.u = *reinterpret_cast<const uint4*>(p);
  return c.s;
}
__device__ __forceinline__ short8 as_short8(uint4 u) {
  union { uint4 u; short8 s; } c; c.u = u; return c.s;
}
__device__ __forceinline__ short8 pack8(const float* v) {
  short8 s;
  #pragma unroll
  for (int e = 0; e < 8; ++e) s[e] = (short)f2bf(v[e]);
  return s;
}
__device__ __forceinline__ float ln64(float y, float g, float be) {
  float s = y, sq = y * y;
  #pragma unroll
  for (int off = 32; off > 0; off >>= 1) {
    s  += __shfl_xor(s, off, 64);
    sq += __shfl_xor(sq, off, 64);
  }
  float mu  = s * 0.015625f;
  float var = sq * 0.015625f - mu * mu;
  return (y - mu) * rsqrtf(var + 1e-5f) * g + be;
}

// ---------------- dtype detect ----------------
__global__ __launch_bounds__(64) void k_detect(const u32* __restrict__ x2,
                                               int* __restrict__ flag) {
  int t = threadIdx.x;
  int bad = 0;
  for (int i = 0; i < 16; ++i) {
    float a = fabsf(lo16(x2[t * 16 + i]));
    if (!(a < 1e4f)) bad = 1;
  }
  int anybad = __any(bad);
  if (t == 0) *flag = anybad ? 1 : 0;   // 1 = fp32 inputs
}

// ---------------- x -> bf16 ----------------
__global__ __launch_bounds__(256) void k_xb(const int* __restrict__ flag,
                                            const void* __restrict__ x,
                                            u16* __restrict__ xb) {
  const int isf = *flag;
  size_t gid = (size_t)blockIdx.x * 256 + threadIdx.x;
  if (isf) {
    const float4* src = (const float4*)x;
    for (size_t i = gid; i < 3145728; i += 1048576) {
      float4 v = src[i];
      ushort4 o;
      o.x = f2bf(v.x); o.y = f2bf(v.y); o.z = f2bf(v.z); o.w = f2bf(v.w);
      ((ushort4*)xb)[i] = o;
    }
  } else {
    const uint4* src = (const uint4*)x;
    for (size_t i = gid; i < 1572864; i += 1048576)
      ((uint4*)xb)[i] = src[i];
  }
}

// ---------------- per-batch column sums of x (fp32 exact) ----------------
__global__ __launch_bounds__(192) void k_xsum(const int* __restrict__ flag,
                                              const void* __restrict__ x,
                                              float* __restrict__ xsum) {
  const int isf = *flag;
  const int t = threadIdx.x;
  const int r0 = blockIdx.x * 256;
  const int b = r0 >> 12;
  float s = 0.f;
  if (isf) {
    const float* xp = (const float*)x;
    for (int r = 0; r < 256; ++r) s += xp[(size_t)(r0 + r) * 192 + t];
  } else {
    const u16* xp = (const u16*)x;
    for (int r = 0; r < 256; ++r) s += bf2f(xp[(size_t)(r0 + r) * 192 + t]);
  }
  atomicAdd(xsum + b * 192 + t, s);
}

// ---------------- build swizzled B operands ----------------
// Bs1:   [ks(6)][nt(16)][l(64)][e(8)]  over [Wq|Wk|Wv|Win] (192x256)
// BsKlo: [ks(6)][nt'(4)][l(64)][e(8)]  Wk lo-part
// Bs2:   [ks(8)][nt(12)][l(64)][e(8)]  over [Wout;Wp] (256x192)
// W1f:   [ks(2)][nt(8)][l(64)][e(8)]   W1 (64x128)
// W2f:   [ks(4)][nt(4)][l(64)][e(8)]   W2 (128x64)
__global__ __launch_bounds__(256) void k_prepw(
    const int* __restrict__ flag,
    const void* Wq, const void* Wk, const void* Wv, const void* Win,
    const void* Wout, const void* Wp, const void* W1, const void* W2,
    const void* bq, const void* bk, const void* bv,
    u16* __restrict__ Bs1, u16* __restrict__ BsKlo, u16* __restrict__ Bs2,
    u16* __restrict__ W1f, u16* __restrict__ W2f, float* __restrict__ bcat)
{
  const int isf = *flag;
  int idx = blockIdx.x * 256 + threadIdx.x;
  if (idx < 49152) {
    int e = idx & 7, l = (idx >> 3) & 63, g = idx >> 9;
    int nt = g & 15, ks = g >> 4;
    int k = ks * 32 + (l >> 4) * 8 + e;
    int n = nt * 16 + (l & 15);
    const void* W = (n < 64) ? Wq : (n < 128) ? Wk : (n < 192) ? Wv : Win;
    Bs1[idx] = f2bf(ldwf(W, k * 64 + (n & 63), isf));
  } else if (idx < 61440) {
    int j = idx - 49152;
    int e = j & 7, l = (j >> 3) & 63, g = j >> 9;
    int ntp = g & 3, ks = g >> 2;
    int k = ks * 32 + (l >> 4) * 8 + e;
    int n = ntp * 16 + (l & 15);
    float wv = ldwf(Wk, k * 64 + n, isf);
    u16 hi = f2bf(wv);
    BsKlo[j] = f2bf(wv - bf2f(hi));
  } else if (idx < 110592) {
    int j = idx - 61440;
    int e = j & 7, l = (j >> 3) & 63, g = j >> 9;
    int nt = g % 12, ks = g / 12;
    int k = ks * 32 + (l >> 4) * 8 + e;
    int n = nt * 16 + (l & 15);
    float v = (k < 64) ? ldwf(Wout, k * 192 + n, isf)
                       : ldwf(Wp, (k - 64) * 192 + n, isf);
    Bs2[j] = f2bf(v);
  } else if (idx < 118784) {
    int j = idx - 110592;
    int e = j & 7, l = (j >> 3) & 63, g = j >> 9;
    int nt = g & 7, ks = g >> 3;
    int k = ks * 32 + (l >> 4) * 8 + e;
    int n = nt * 16 + (l & 15);
    W1f[j] = f2bf(ldwf(W1, k * 128 + n, isf));
  } else if (idx < 126976) {
    int j = idx - 118784;
    int e = j & 7, l = (j >> 3) & 63, g = j >> 9;
    int nt = g & 3, ks = g >> 2;
    int k = ks * 32 + (l >> 4) * 8 + e;
    int n = nt * 16 + (l & 15);
    W2f[j] = f2bf(ldwf(W2, k * 64 + n, isf));
  } else if (idx < 127232) {
    int n = idx - 126976;
    bcat[n] = (n < 64)  ? ldwf(bq, n, isf)
            : (n < 128) ? ldwf(bk, n - 64, isf)
            : (n < 192) ? ldwf(bv, n - 128, isf) : 0.f;
  }
}

// ---------------- GEMM1 fused with stats (r12; bf16 path reads x directly) --
// 2048 blocks x 512 thr (8 waves), 32 rows/block, STATIC roles.
template<bool F32>
__device__ void gemm1_body(const void* __restrict__ x,
                           const u16* __restrict__ Bs1,
                           const u16* __restrict__ BsKlo,
                           const float* __restrict__ bcat,
                           u16* __restrict__ C1, float* __restrict__ stats,
                           float (*xs)[196], float (*Ks)[65], float (*Vs)[65])
{
  const int tid = threadIdx.x;
  const int mbase = blockIdx.x * 32;
  const int b = mbase >> 12;

  if constexpr (F32) {
    for (int i = tid; i < 1536; i += 512) {
      int row = i / 48, c4 = i - row * 48;
      float4 v = *((const float4*)x + (size_t)(mbase + row) * 48 + c4);
      *(float4*)&xs[row][c4 * 4] = v;
    }
    __syncthreads();
  }
  // bf16 path: no staging needed — A-fragments load directly from global x.

  const int w = tid >> 6, l = tid & 63, lm = l & 15, lk = l >> 4;
  const int nt0 = w * 2;
  const bool isK = (w == 2) || (w == 3);

  short8 bhi[2][6], blo[2][6];
  #pragma unroll
  for (int n2 = 0; n2 < 2; ++n2)
    #pragma unroll
    for (int ks = 0; ks < 6; ++ks) {
      bhi[n2][ks] = ld_frag8(Bs1 + (size_t)((ks * 16 + nt0 + n2) * 64 + l) * 8);
      if (F32 && isK)
        blo[n2][ks] = ld_frag8(BsKlo + (size_t)((ks * 4 + nt0 + n2 - 4) * 64 + l) * 8);
    }
  float bias[2];
  bias[0] = bcat[nt0 * 16 + lm];
  bias[1] = bcat[(nt0 + 1) * 16 + lm];

  for (int mt = 0; mt < 2; ++mt) {
    short8 ahi[6], alo[6];
    if constexpr (F32) {
      const float* xr = &xs[mt * 16 + lm][0];
      #pragma unroll
      for (int ks = 0; ks < 6; ++ks) {
        float v[8];
        *(float4*)&v[0] = *(const float4*)(xr + ks * 32 + lk * 8);
        *(float4*)&v[4] = *(const float4*)(xr + ks * 32 + lk * 8 + 4);
        short8 h8;
        #pragma unroll
        for (int e = 0; e < 8; ++e) h8[e] = (short)f2bf(v[e]);
        ahi[ks] = h8;
        if (isK) {
          short8 l8;
          #pragma unroll
          for (int e = 0; e < 8; ++e) {
            float r = v[e] - bf2f((u16)h8[e]);
            l8[e] = (short)f2bf(r);
          }
          alo[ks] = l8;
        }
      }
    } else {
      const u16* xg = (const u16*)x + (size_t)(mbase + mt * 16 + lm) * 192 + lk * 8;
      #pragma unroll
      for (int ks = 0; ks < 6; ++ks) ahi[ks] = ld_frag8(xg + ks * 32);
    }
    f32x4 acc[2];
    #pragma unroll
    for (int n2 = 0; n2 < 2; ++n2) {
      f32x4 a = {bias[n2], bias[n2], bias[n2], bias[n2]};
      acc[n2] = a;
    }
    #pragma unroll
    for (int ks = 0; ks < 6; ++ks)
      #pragma unroll
      for (int n2 = 0; n2 < 2; ++n2) {
        acc[n2] = MFMA16(ahi[ks], bhi[n2][ks], acc[n2], 0, 0, 0);
        if (F32 && isK) {
          acc[n2] = MFMA16(ahi[ks], blo[n2][ks], acc[n2], 0, 0, 0);
          acc[n2] = MFMA16(alo[ks], bhi[n2][ks], acc[n2], 0, 0, 0);
          acc[n2] = MFMA16(alo[ks], blo[n2][ks], acc[n2], 0, 0, 0);
        }
      }
    const int rl = mt * 16 + lk * 4;
    if (w < 2) {
      #pragma unroll
      for (int n2 = 0; n2 < 2; ++n2)
        #pragma unroll
        for (int r = 0; r < 4; ++r)
          C1[(size_t)(mbase + rl + r) * 128 + (nt0 + n2) * 16 + lm] = f2bf(acc[n2][r]);
    } else if (isK) {
      #pragma unroll
      for (int n2 = 0; n2 < 2; ++n2)
        #pragma unroll
        for (int r = 0; r < 4; ++r)
          Ks[rl + r][(nt0 + n2 - 4) * 16 + lm] = acc[n2][r];
    } else if (w < 6) {
      #pragma unroll
      for (int n2 = 0; n2 < 2; ++n2)
        #pragma unroll
        for (int r = 0; r < 4; ++r)
          Vs[rl + r][(nt0 + n2 - 8) * 16 + lm] = acc[n2][r];
    } else {
      #pragma unroll
      for (int n2 = 0; n2 < 2; ++n2)
        #pragma unroll
        for (int r = 0; r < 4; ++r)
          C1[(size_t)(mbase + rl + r) * 128 + 64 + (nt0 + n2 - 12) * 16 + lm] = f2bf(acc[n2][r]);
    }
  }
  __syncthreads();

  float* sb = stats + (size_t)(b * 4) * 832;
  #pragma unroll
  for (int it = 0; it < 2; ++it) {
    int item = tid + it * 512;
    int hh = item >> 8, f = (item >> 4) & 15, c = item & 15;
    float a1 = 0.f, a2 = 0.f, a3 = 0.f;
    for (int r = 0; r < 32; ++r) {
      float kv = Ks[r][hh * 16 + f];
      float vv = Vs[r][hh * 16 + c];
      float k2 = kv * kv;
      a1 = fmaf(kv, vv, a1);
      a2 = fmaf(k2, vv, a2);
      a3 = fmaf(k2 * kv, vv, a3);
    }
    float* base = sb + (size_t)hh * 832 + f * 16 + c;
    atomicAdd(base, a1);
    atomicAdd(base + 256, a2);
    atomicAdd(base + 512, a3);
  }
  if (tid < 192) {
    int kk = tid >> 6, hf = tid & 63, h2 = hf >> 4, ff = hf & 15;
    float s = 0.f;
    for (int r = 0; r < 32; ++r) {
      float kv = Ks[r][hf];
      s += (kk == 0) ? kv : (kk == 1) ? kv * kv : kv * kv * kv;
    }
    atomicAdd(sb + (size_t)h2 * 832 + 768 + kk * 16 + ff, s);
  } else if (tid < 256) {
    int hf = tid - 192, h2 = hf >> 4;
    float s = 0.f;
    for (int r = 0; r < 32; ++r) s += Vs[r][hf];
    atomicAdd(sb + (size_t)h2 * 832 + 816 + (hf & 15), s);
  }
}

__global__ __launch_bounds__(512, 2) void k_gemm1(
    const int* __restrict__ flag, const void* __restrict__ x,
    const u16* __restrict__ Bs1, const u16* __restrict__ BsKlo,
    const float* __restrict__ bcat,
    u16* __restrict__ C1, float* __restrict__ stats)
{
  __shared__ float xs[32][196];
  __shared__ float Ks[32][65];
  __shared__ float Vs[32][65];
  if (*flag) gemm1_body<true >(x, Bs1, BsKlo, bcat, C1, stats, xs, Ks, Vs);
  else       gemm1_body<false>(x, Bs1, BsKlo, bcat, C1, stats, xs, Ks, Vs);
}

// ---------------- finalize (exact sumN1 via xsum) ----------------
template<bool F32>
__device__ void finalize_body(const float* stats, const void* Pi,
                              const void* Wk, const void* bk,
                              const float* xsum, float* M, float* sn1)
{
  const int bh = blockIdx.x, bb = bh >> 2, h = bh & 3, t = threadIdx.x;
  const float* sb = stats + (size_t)bh * 832;
  float* mb = M + (size_t)bh * 784;
  const float inv6 = 1.0f / 6.0f;

  {
    int f = t >> 4, s = t & 15;
    float p = 0.f;
    for (int i = s * 12; i < s * 12 + 12; ++i)
      p += xsum[bb * 192 + i] * ldwf(Wk, i * 64 + h * 16 + f, F32);
    p += __shfl_xor(p, 1, 64);
    p += __shfl_xor(p, 2, 64);
    p += __shfl_xor(p, 4, 64);
    p += __shfl_xor(p, 8, 64);
    if (s == 0) sn1[f] = p + 4096.0f * ldwf(bk, h * 16 + f, F32);
  }
  __syncthreads();

  {
    const int f = t >> 4, c = t & 15;
    #pragma unroll
    for (int k = 0; k < 3; ++k) {
      float fkv = sb[k * 256 + f * 16 + c];
      float sk  = (k == 0) ? sn1[f] : sb[768 + k * 16 + f];
      float pi  = ldwf(Pi, h * 4 + (k + 1), F32);
      mb[k * 256 + f * 16 + c] = fkv / ((sk + 1e-8f) * 4.0f) * pi * inv6;
    }
  }
  if (t < 16) {
    float sv  = sb[816 + t];
    float pi0 = ldwf(Pi, h * 4 + 0, F32);
    mb[768 + t] = sv / (4096.0f + 1e-8f) * pi0 * inv6;
  }
}

__global__ __launch_bounds__(256) void k_finalize(
    const int* __restrict__ flag, const float* __restrict__ stats,
    const void* __restrict__ Pi, const void* __restrict__ Wk,
    const void* __restrict__ bk, const float* __restrict__ xsum,
    float* __restrict__ M)
{
  __shared__ float sn1[16];
  if (*flag) finalize_body<true >(stats, Pi, Wk, bk, xsum, M, sn1);
  else       finalize_body<false>(stats, Pi, Wk, bk, xsum, M, sn1);
}

// ---------------- mid: MFMA att + LN + MFMA FFN + LN ---------
template<bool F32> __device__ void mid_body(
    const u16* __restrict__ C1, u16* __restrict__ R2,
    const float* __restrict__ Mall,
    const u16* __restrict__ W1f, const u16* __restrict__ W2f,
    const void* __restrict__ b1, const void* __restrict__ b2,
    const void* __restrict__ lng, const void* __restrict__ lnb,
    float (*attL)[72], u16 (*resB)[72], u16 (*hB)[136])
{
  const int tid = threadIdx.x;
  const int w = tid >> 6, l = tid & 63;
  const int lm = l & 15, lk = l >> 4;
  const int n0g = blockIdx.x * 64;
  const int b = n0g >> 12;
  const int n2_0 = n0g & 4095;
  const int h = n2_0 >> 10;
  const int qg0 = (b << 12) + ((n2_0 & 1023) << 2);
  const float* mb = Mall + (size_t)((b << 2) + h) * 784;

  short8 Bhi[2], Blo[2];
  #pragma unroll
  for (int ks = 0; ks < 2; ++ks) {
    float vh[8], vl[8];
    #pragma unroll
    for (int e = 0; e < 8; ++e) {
      int kk = ks * 32 + lk * 8 + e;
      float v = (kk < 16) ? mb[kk * 16 + lm]
              : (kk < 32) ? mb[256 + (kk - 16) * 16 + lm]
              : (kk < 48) ? mb[512 + (kk - 32) * 16 + lm] : 0.f;
      float hi = bf2f(f2bf(v));
      vh[e] = hi; vl[e] = v - hi;
    }
    Bhi[ks] = pack8(vh);
    Blo[ks] = pack8(vl);
  }
  const float c0v = mb[768 + lm];

  #pragma unroll
  for (int mt2 = 0; mt2 < 4; ++mt2) {
    const int mt = w * 4 + mt2;
    uint4 qv = *(const uint4*)(C1 + (size_t)(qg0 + mt * 16 + lm) * 128
                               + h * 16 + (lk & 1) * 8);
    float q[8] = {lo16(qv.x), hi16(qv.x), lo16(qv.y), hi16(qv.y),
                  lo16(qv.z), hi16(qv.z), lo16(qv.w), hi16(qv.w)};
    float q2[8], q3[8];
    #pragma unroll
    for (int e = 0; e < 8; ++e) { q2[e] = q[e] * q[e]; q3[e] = q2[e] * q[e]; }
    short8 a1, a2;
    if (lk < 2) { a1 = as_short8(qv); a2 = pack8(q3); }
    else        { a1 = pack8(q2);     a2 = short8{0,0,0,0,0,0,0,0}; }

    f32x4 acc = {c0v, c0v, c0v, c0v};
    acc = MFMA16(a1, Bhi[0], acc, 0, 0, 0);
    acc = MFMA16(a1, Blo[0], acc, 0, 0, 0);
    acc = MFMA16(a2, Bhi[1], acc, 0, 0, 0);
    acc = MFMA16(a2, Blo[1], acc, 0, 0, 0);

    #pragma unroll
    for (int r = 0; r < 4; ++r) {
      int qr = mt * 16 + lk * 4 + r;
      attL[qr >> 2][(qr & 3) * 16 + lm] = acc[r];
    }
  }

  const float gj = ldwf(lng, l, F32), bj = ldwf(lnb, l, F32);
  #pragma unroll 4
  for (int rr = 0; rr < 16; ++rr) {
    int r = w * 16 + rr;
    float proj = bf2f(C1[(size_t)(n0g + r) * 128 + 64 + l]);
    float y = proj + attL[r][l];
    resB[r][l] = f2bf(ln64(y, gj, bj));
  }

  short8 a0 = *(const short8*)&resB[w * 16 + lm][lk * 8];
  short8 a1f = *(const short8*)&resB[w * 16 + lm][32 + lk * 8];
  f32x4 hacc[8];
  #pragma unroll
  for (int nt = 0; nt < 8; ++nt) {
    float bv = ldwf(b1, nt * 16 + lm, F32);
    f32x4 a = {bv, bv, bv, bv};
    hacc[nt] = a;
  }
  #pragma unroll
  for (int nt = 0; nt < 8; ++nt) {
    short8 w1a = ld_frag8(W1f + (size_t)((0 * 8 + nt) * 64 + l) * 8);
    short8 w1b = ld_frag8(W1f + (size_t)((1 * 8 + nt) * 64 + l) * 8);
    hacc[nt] = MFMA16(a0, w1a, hacc[nt], 0, 0, 0);
    hacc[nt] = MFMA16(a1f, w1b, hacc[nt], 0, 0, 0);
  }
  #pragma unroll
  for (int nt = 0; nt < 8; ++nt)
    #pragma unroll
    for (int r = 0; r < 4; ++r) {
      int row = w * 16 + lk * 4 + r;
      hB[row][nt * 16 + lm] = f2bf(fmaxf(hacc[nt][r], 0.f));
    }

  short8 ha[4];
  #pragma unroll
  for (int ks = 0; ks < 4; ++ks)
    ha[ks] = *(const short8*)&hB[w * 16 + lm][ks * 32 + lk * 8];
  f32x4 oacc[4];
  #pragma unroll
  for (int nt = 0; nt < 4; ++nt) {
    float bv = ldwf(b2, nt * 16 + lm, F32);
    f32x4 a = {bv, bv, bv, bv};
    oacc[nt] = a;
  }
  #pragma unroll
  for (int ks = 0; ks < 4; ++ks)
    #pragma unroll
    for (int nt = 0; nt < 4; ++nt) {
      short8 w2v = ld_frag8(W2f + (size_t)((ks * 4 + nt) * 64 + l) * 8);
      oacc[nt] = MFMA16(ha[ks], w2v, oacc[nt], 0, 0, 0);
    }

  float gcol[4], bcol[4];
  #pragma unroll
  for (int nt = 0; nt < 4; ++nt) {
    gcol[nt] = ldwf(lng, nt * 16 + lm, F32);
    bcol[nt] = ldwf(lnb, nt * 16 + lm, F32);
  }
  #pragma unroll
  for (int r = 0; r < 4; ++r) {
    int row = w * 16 + lk * 4 + r;
    float y[4];
    float s = 0.f, sq = 0.f;
    #pragma unroll
    for (int nt = 0; nt < 4; ++nt) {
      y[nt] = oacc[nt][r] + bf2f(resB[row][nt * 16 + lm]);
      s += y[nt];
      sq = fmaf(y[nt], y[nt], sq);
    }
    #pragma unroll
    for (int off = 8; off > 0; off >>= 1) {
      s  += __shfl_xor(s, off, 64);
      sq += __shfl_xor(sq, off, 64);
    }
    float mu = s * 0.015625f;
    float var = sq * 0.015625f - mu * mu;
    float rs = rsqrtf(var + 1e-5f);
    #pragma unroll
    for (int nt = 0; nt < 4; ++nt) {
      float r2v = (y[nt] - mu) * rs * gcol[nt] + bcol[nt];
      R2[(size_t)(n0g + row) * 64 + nt * 16 + lm] = f2bf(r2v);
    }
  }
}

__global__ __launch_bounds__(256, 2) void k_mid(
    const int* __restrict__ flag, const u16* __restrict__ C1,
    u16* __restrict__ R2, const float* __restrict__ Mall,
    const u16* __restrict__ W1f, const u16* __restrict__ W2f,
    const void* __restrict__ b1, const void* __restrict__ b2,
    const void* __restrict__ lng, const void* __restrict__ lnb)
{
  __shared__ float attL[64][72];
  __shared__ u16 resB[64][72];
  __shared__ u16 hB[64][136];
  if (*flag) mid_body<true >(C1, R2, Mall, W1f, W2f, b1, b2, lng, lnb, attL, resB, hB);
  else       mid_body<false>(C1, R2, Mall, W1f, W2f, b1, b2, lng, lnb, attL, resB, hB);
}

// ---------------- GEMM2: out = [res2|x] @ [Wout;Wp] + bout ---
__global__ __launch_bounds__(256, 2) void k_gemm2(
    const int* __restrict__ flag,
    const u16* __restrict__ R2, const u16* __restrict__ xb,
    const u16* __restrict__ Bs2, const void* __restrict__ bout,
    void* __restrict__ out)
{
  const int isf = *flag;
  const int l = threadIdx.x & 63;
  const int w = threadIdx.x >> 6;
  const int mbase = blockIdx.x * 64;
  const int lm = l & 15, lk = l >> 4;

  short8 bf[8][3];
  #pragma unroll
  for (int ks = 0; ks < 8; ++ks)
    #pragma unroll
    for (int nt = 0; nt < 3; ++nt)
      bf[ks][nt] = ld_frag8(Bs2 + (size_t)((ks * 12 + w * 3 + nt) * 64 + l) * 8);

  float bias[3];
  #pragma unroll
  for (int nt = 0; nt < 3; ++nt) bias[nt] = ldwf(bout, w * 48 + nt * 16 + lm, isf);

  short8 af[8];
  {
    const int row = mbase + lm;
    const u16* rp = R2 + (size_t)row * 64 + lk * 8;
    af[0] = ld_frag8(rp);
    af[1] = ld_frag8(rp + 32);
    const u16* xp = xb + (size_t)row * IND + lk * 8;
    #pragma unroll
    for (int ks = 2; ks < 8; ++ks) af[ks] = ld_frag8(xp + (ks - 2) * 32);
  }

  for (int mt = 0; mt < 4; ++mt) {
    short8 afn[8];
    if (mt < 3) {
      const int row = mbase + (mt + 1) * 16 + lm;
      const u16* rp = R2 + (size_t)row * 64 + lk * 8;
      afn[0] = ld_frag8(rp);
      afn[1] = ld_frag8(rp + 32);
      const u16* xp = xb + (size_t)row * IND + lk * 8;
      #pragma unroll
      for (int ks = 2; ks < 8; ++ks) afn[ks] = ld_frag8(xp + (ks - 2) * 32);
    }
    f32x4 acc[3];
    #pragma unroll
    for (int nt = 0; nt < 3; ++nt) {
      f32x4 a = {bias[nt], bias[nt], bias[nt], bias[nt]};
      acc[nt] = a;
    }
    #pragma unroll
    for (int ks = 0; ks < 8; ++ks)
      #pragma unroll
      for (int nt = 0; nt < 3; ++nt)
        acc[nt] = MFMA16(af[ks], bf[ks][nt], acc[nt], 0, 0, 0);
    const int r0 = mbase + mt * 16 + lk * 4;
    const int c0 = w * 48 + lm;
    if (isf) {
      float* op = (float*)out;
      #pragma unroll
      for (int nt = 0; nt < 3; ++nt)
        #pragma unroll
        for (int r = 0; r < 4; ++r)
          op[(size_t)(r0 + r) * IND + c0 + nt * 16] = acc[nt][r];
    } else {
      u16* op = (u16*)out;
      #pragma unroll
      for (int nt = 0; nt < 3; ++nt)
        #pragma unroll
        for (int r = 0; r < 4; ++r)
          op[(size_t)(r0 + r) * IND + c0 + nt * 16] = f2bf(acc[nt][r]);
    }
    #pragma unroll
    for (int ks = 0; ks < 8; ++ks) af[ks] = afn[ks];
  }
}

extern "C" void kernel_launch(void* const* d_in, const int* in_sizes, int n_in,
                              void* d_out, int out_size, void* d_ws, size_t ws_size,
                              hipStream_t stream)
{
  const void* x   = d_in[0];
  const void* Wq  = d_in[1];
  const void* bq  = d_in[2];
  const void* Wk  = d_in[3];
  const void* bk  = d_in[4];
  const void* Wv  = d_in[5];
  const void* bv  = d_in[6];
  const void* Win = d_in[7];
  const void* Wout= d_in[8];
  const void* bout= d_in[9];
  const void* W1  = d_in[10];
  const void* b1  = d_in[11];
  const void* W2  = d_in[12];
  const void* b2  = d_in[13];
  const void* lng = d_in[14];
  const void* lnb = d_in[15];
  const void* Wp  = d_in[16];
  const void* Pi  = d_in[17];

  u16* xb    = (u16*)d_ws;                  // 12,582,912
  u16* C1    = xb + (size_t)12582912;       // 8,388,608  (Q | proj)
  u16* R2    = C1 + (size_t)8388608;        // 4,194,304  (res2)
  u16* Bs1   = R2 + (size_t)4194304;        // 49,152
  u16* BsKlo = Bs1 + 49152;                 // 12,288
  u16* Bs2   = BsKlo + 12288;               // 49,152
  u16* W1f   = Bs2 + 49152;                 // 8,192
  u16* W2f   = W1f + 8192;                  // 8,192
  float* bcat  = (float*)(W2f + 8192);      // 256
  float* stats = bcat + 256;                // 53,248
  float* xsum  = stats + 53248;             // 3,072
  float* Mc    = xsum + 3072;               // 50,176
  int*   flag  = (int*)(Mc + 50176);

  k_detect<<<1, 64, 0, stream>>>((const u32*)x, flag);
  hipMemsetAsync(stats, 0, (size_t)(53248 + 3072) * sizeof(float), stream);

  k_prepw<<<497, 256, 0, stream>>>(flag, Wq, Wk, Wv, Win, Wout, Wp, W1, W2,
                                   bq, bk, bv, Bs1, BsKlo, Bs2, W1f, W2f, bcat);
  k_xb<<<4096, 256, 0, stream>>>(flag, x, xb);
  k_xsum<<<256, 192, 0, stream>>>(flag, x, xsum);
  k_gemm1<<<2048, 512, 0, stream>>>(flag, x, Bs1, BsKlo, bcat, C1, stats);
  k_finalize<<<64, 256, 0, stream>>>(flag, stats, Pi, Wk, bk, xsum, Mc);
  k_mid<<<1024, 256, 0, stream>>>(flag, C1, R2, Mc, W1f, W2f, b1, b2, lng, lnb);
  k_gemm2<<<1024, 256, 0, stream>>>(flag, R2, xb, Bs2, bout, d_out);
}

// Round 18
// 159.027 us; speedup vs baseline: 1.2643x; 1.0187x over previous
//
#include <hip/hip_runtime.h>

typedef unsigned int u32;
typedef unsigned short u16;

#define NB 16
#define NN 4096
#define IND 192

typedef __attribute__((ext_vector_type(8))) short short8;
typedef __attribute__((ext_vector_type(4))) float f32x4;
#define MFMA16 __builtin_amdgcn_mfma_f32_16x16x32_bf16

__device__ __forceinline__ float bf2f(u16 u) {
  union { u32 i; float f; } c; c.i = ((u32)u) << 16; return c.f;
}
__device__ __forceinline__ float lo16(u32 u) {
  union { u32 i; float f; } c; c.i = u << 16; return c.f;
}
__device__ __forceinline__ float hi16(u32 u) {
  union { u32 i; float f; } c; c.i = u & 0xffff0000u; return c.f;
}
__device__ __forceinline__ u16 f2bf(float f) {
  union { float f; u32 i; } c; c.f = f;
  u32 r = c.i + 0x7fffu + ((c.i >> 16) & 1u);  // RNE
  return (u16)(r >> 16);
}
__device__ __forceinline__ float ldwf(const void* p, int i, int isf) {
  return isf ? ((const float*)p)[i] : bf2f(((const u16*)p)[i]);
}
__device__ __forceinline__ short8 ld_frag8(const u16* p) {
  union { uint4 u; short8 s; } c;
  c.u = *reinterpret_cast<const uint4*>(p);
  return c.s;
}
__device__ __forceinline__ short8 as_short8(uint4 u) {
  union { uint4 u; short8 s; } c; c.u = u; return c.s;
}
__device__ __forceinline__ short8 pack8(const float* v) {
  short8 s;
  #pragma unroll
  for (int e = 0; e < 8; ++e) s[e] = (short)f2bf(v[e]);
  return s;
}
__device__ __forceinline__ short8 packf4(float4 a, float4 b) {
  short8 s;
  s[0] = (short)f2bf(a.x); s[1] = (short)f2bf(a.y);
  s[2] = (short)f2bf(a.z); s[3] = (short)f2bf(a.w);
  s[4] = (short)f2bf(b.x); s[5] = (short)f2bf(b.y);
  s[6] = (short)f2bf(b.z); s[7] = (short)f2bf(b.w);
  return s;
}
__device__ __forceinline__ float ln64(float y, float g, float be) {
  float s = y, sq = y * y;
  #pragma unroll
  for (int off = 32; off > 0; off >>= 1) {
    s  += __shfl_xor(s, off, 64);
    sq += __shfl_xor(sq, off, 64);
  }
  float mu  = s * 0.015625f;
  float var = sq * 0.015625f - mu * mu;
  return (y - mu) * rsqrtf(var + 1e-5f) * g + be;
}

// ---------------- dtype detect ----------------
__global__ __launch_bounds__(64) void k_detect(const u32* __restrict__ x2,
                                               int* __restrict__ flag) {
  int t = threadIdx.x;
  int bad = 0;
  for (int i = 0; i < 16; ++i) {
    float a = fabsf(lo16(x2[t * 16 + i]));
    if (!(a < 1e4f)) bad = 1;
  }
  int anybad = __any(bad);
  if (t == 0) *flag = anybad ? 1 : 0;   // 1 = fp32 inputs
}

// ---------------- per-batch column sums of x (fp32 exact) ----------------
__global__ __launch_bounds__(192) void k_xsum(const int* __restrict__ flag,
                                              const void* __restrict__ x,
                                              float* __restrict__ xsum) {
  const int isf = *flag;
  const int t = threadIdx.x;
  const int r0 = blockIdx.x * 256;
  const int b = r0 >> 12;
  float s = 0.f;
  if (isf) {
    const float* xp = (const float*)x;
    for (int r = 0; r < 256; ++r) s += xp[(size_t)(r0 + r) * 192 + t];
  } else {
    const u16* xp = (const u16*)x;
    for (int r = 0; r < 256; ++r) s += bf2f(xp[(size_t)(r0 + r) * 192 + t]);
  }
  atomicAdd(xsum + b * 192 + t, s);
}

// ---------------- build swizzled B operands ----------------
// Bs1:   [ks(6)][nt(16)][l(64)][e(8)]  over [Wq|Wk|Wv|Win] (192x256)
// BsKlo: [ks(6)][nt'(4)][l(64)][e(8)]  Wk lo-part
// Bs2:   [ks(8)][nt(12)][l(64)][e(8)]  over [Wout;Wp] (256x192)
// W1f:   [ks(2)][nt(8)][l(64)][e(8)]   W1 (64x128)
// W2f:   [ks(4)][nt(4)][l(64)][e(8)]   W2 (128x64)
__global__ __launch_bounds__(256) void k_prepw(
    const int* __restrict__ flag,
    const void* Wq, const void* Wk, const void* Wv, const void* Win,
    const void* Wout, const void* Wp, const void* W1, const void* W2,
    const void* bq, const void* bk, const void* bv,
    u16* __restrict__ Bs1, u16* __restrict__ BsKlo, u16* __restrict__ Bs2,
    u16* __restrict__ W1f, u16* __restrict__ W2f, float* __restrict__ bcat)
{
  const int isf = *flag;
  int idx = blockIdx.x * 256 + threadIdx.x;
  if (idx < 49152) {
    int e = idx & 7, l = (idx >> 3) & 63, g = idx >> 9;
    int nt = g & 15, ks = g >> 4;
    int k = ks * 32 + (l >> 4) * 8 + e;
    int n = nt * 16 + (l & 15);
    const void* W = (n < 64) ? Wq : (n < 128) ? Wk : (n < 192) ? Wv : Win;
    Bs1[idx] = f2bf(ldwf(W, k * 64 + (n & 63), isf));
  } else if (idx < 61440) {
    int j = idx - 49152;
    int e = j & 7, l = (j >> 3) & 63, g = j >> 9;
    int ntp = g & 3, ks = g >> 2;
    int k = ks * 32 + (l >> 4) * 8 + e;
    int n = ntp * 16 + (l & 15);
    float wv = ldwf(Wk, k * 64 + n, isf);
    u16 hi = f2bf(wv);
    BsKlo[j] = f2bf(wv - bf2f(hi));
  } else if (idx < 110592) {
    int j = idx - 61440;
    int e = j & 7, l = (j >> 3) & 63, g = j >> 9;
    int nt = g % 12, ks = g / 12;
    int k = ks * 32 + (l >> 4) * 8 + e;
    int n = nt * 16 + (l & 15);
    float v = (k < 64) ? ldwf(Wout, k * 192 + n, isf)
                       : ldwf(Wp, (k - 64) * 192 + n, isf);
    Bs2[j] = f2bf(v);
  } else if (idx < 118784) {
    int j = idx - 110592;
    int e = j & 7, l = (j >> 3) & 63, g = j >> 9;
    int nt = g & 7, ks = g >> 3;
    int k = ks * 32 + (l >> 4) * 8 + e;
    int n = nt * 16 + (l & 15);
    W1f[j] = f2bf(ldwf(W1, k * 128 + n, isf));
  } else if (idx < 126976) {
    int j = idx - 118784;
    int e = j & 7, l = (j >> 3) & 63, g = j >> 9;
    int nt = g & 3, ks = g >> 2;
    int k = ks * 32 + (l >> 4) * 8 + e;
    int n = nt * 16 + (l & 15);
    W2f[j] = f2bf(ldwf(W2, k * 64 + n, isf));
  } else if (idx < 127232) {
    int n = idx - 126976;
    bcat[n] = (n < 64)  ? ldwf(bq, n, isf)
            : (n < 128) ? ldwf(bk, n - 64, isf)
            : (n < 192) ? ldwf(bv, n - 128, isf) : 0.f;
  }
}

// ---------------- GEMM1 fused with stats (r17 verbatim; 4-term K kept) ------
// 2048 blocks x 512 thr (8 waves), 32 rows/block, STATIC roles.
template<bool F32>
__device__ void gemm1_body(const void* __restrict__ x,
                           const u16* __restrict__ Bs1,
                           const u16* __restrict__ BsKlo,
                           const float* __restrict__ bcat,
                           u16* __restrict__ C1, float* __restrict__ stats,
                           float (*xs)[196], float (*Ks)[65], float (*Vs)[65])
{
  const int tid = threadIdx.x;
  const int mbase = blockIdx.x * 32;
  const int b = mbase >> 12;

  if constexpr (F32) {
    for (int i = tid; i < 1536; i += 512) {
      int row = i / 48, c4 = i - row * 48;
      float4 v = *((const float4*)x + (size_t)(mbase + row) * 48 + c4);
      *(float4*)&xs[row][c4 * 4] = v;
    }
    __syncthreads();
  }

  const int w = tid >> 6, l = tid & 63, lm = l & 15, lk = l >> 4;
  const int nt0 = w * 2;
  const bool isK = (w == 2) || (w == 3);

  short8 bhi[2][6], blo[2][6];
  #pragma unroll
  for (int n2 = 0; n2 < 2; ++n2)
    #pragma unroll
    for (int ks = 0; ks < 6; ++ks) {
      bhi[n2][ks] = ld_frag8(Bs1 + (size_t)((ks * 16 + nt0 + n2) * 64 + l) * 8);
      if (F32 && isK)
        blo[n2][ks] = ld_frag8(BsKlo + (size_t)((ks * 4 + nt0 + n2 - 4) * 64 + l) * 8);
    }
  float bias[2];
  bias[0] = bcat[nt0 * 16 + lm];
  bias[1] = bcat[(nt0 + 1) * 16 + lm];

  for (int mt = 0; mt < 2; ++mt) {
    short8 ahi[6], alo[6];
    if constexpr (F32) {
      const float* xr = &xs[mt * 16 + lm][0];
      #pragma unroll
      for (int ks = 0; ks < 6; ++ks) {
        float v[8];
        *(float4*)&v[0] = *(const float4*)(xr + ks * 32 + lk * 8);
        *(float4*)&v[4] = *(const float4*)(xr + ks * 32 + lk * 8 + 4);
        short8 h8;
        #pragma unroll
        for (int e = 0; e < 8; ++e) h8[e] = (short)f2bf(v[e]);
        ahi[ks] = h8;
        if (isK) {
          short8 l8;
          #pragma unroll
          for (int e = 0; e < 8; ++e) {
            float r = v[e] - bf2f((u16)h8[e]);
            l8[e] = (short)f2bf(r);
          }
          alo[ks] = l8;
        }
      }
    } else {
      const u16* xg = (const u16*)x + (size_t)(mbase + mt * 16 + lm) * 192 + lk * 8;
      #pragma unroll
      for (int ks = 0; ks < 6; ++ks) ahi[ks] = ld_frag8(xg + ks * 32);
    }
    f32x4 acc[2];
    #pragma unroll
    for (int n2 = 0; n2 < 2; ++n2) {
      f32x4 a = {bias[n2], bias[n2], bias[n2], bias[n2]};
      acc[n2] = a;
    }
    #pragma unroll
    for (int ks = 0; ks < 6; ++ks)
      #pragma unroll
      for (int n2 = 0; n2 < 2; ++n2) {
        acc[n2] = MFMA16(ahi[ks], bhi[n2][ks], acc[n2], 0, 0, 0);
        if (F32 && isK) {
          acc[n2] = MFMA16(ahi[ks], blo[n2][ks], acc[n2], 0, 0, 0);
          acc[n2] = MFMA16(alo[ks], bhi[n2][ks], acc[n2], 0, 0, 0);
          acc[n2] = MFMA16(alo[ks], blo[n2][ks], acc[n2], 0, 0, 0);
        }
      }
    const int rl = mt * 16 + lk * 4;
    if (w < 2) {
      #pragma unroll
      for (int n2 = 0; n2 < 2; ++n2)
        #pragma unroll
        for (int r = 0; r < 4; ++r)
          C1[(size_t)(mbase + rl + r) * 128 + (nt0 + n2) * 16 + lm] = f2bf(acc[n2][r]);
    } else if (isK) {
      #pragma unroll
      for (int n2 = 0; n2 < 2; ++n2)
        #pragma unroll
        for (int r = 0; r < 4; ++r)
          Ks[rl + r][(nt0 + n2 - 4) * 16 + lm] = acc[n2][r];
    } else if (w < 6) {
      #pragma unroll
      for (int n2 = 0; n2 < 2; ++n2)
        #pragma unroll
        for (int r = 0; r < 4; ++r)
          Vs[rl + r][(nt0 + n2 - 8) * 16 + lm] = acc[n2][r];
    } else {
      #pragma unroll
      for (int n2 = 0; n2 < 2; ++n2)
        #pragma unroll
        for (int r = 0; r < 4; ++r)
          C1[(size_t)(mbase + rl + r) * 128 + 64 + (nt0 + n2 - 12) * 16 + lm] = f2bf(acc[n2][r]);
    }
  }
  __syncthreads();

  float* sb = stats + (size_t)(b * 4) * 832;
  #pragma unroll
  for (int it = 0; it < 2; ++it) {
    int item = tid + it * 512;
    int hh = item >> 8, f = (item >> 4) & 15, c = item & 15;
    float a1 = 0.f, a2 = 0.f, a3 = 0.f;
    for (int r = 0; r < 32; ++r) {
      float kv = Ks[r][hh * 16 + f];
      float vv = Vs[r][hh * 16 + c];
      float k2 = kv * kv;
      a1 = fmaf(kv, vv, a1);
      a2 = fmaf(k2, vv, a2);
      a3 = fmaf(k2 * kv, vv, a3);
    }
    float* base = sb + (size_t)hh * 832 + f * 16 + c;
    atomicAdd(base, a1);
    atomicAdd(base + 256, a2);
    atomicAdd(base + 512, a3);
  }
  if (tid < 192) {
    int kk = tid >> 6, hf = tid & 63, h2 = hf >> 4, ff = hf & 15;
    float s = 0.f;
    for (int r = 0; r < 32; ++r) {
      float kv = Ks[r][hf];
      s += (kk == 0) ? kv : (kk == 1) ? kv * kv : kv * kv * kv;
    }
    atomicAdd(sb + (size_t)h2 * 832 + 768 + kk * 16 + ff, s);
  } else if (tid < 256) {
    int hf = tid - 192, h2 = hf >> 4;
    float s = 0.f;
    for (int r = 0; r < 32; ++r) s += Vs[r][hf];
    atomicAdd(sb + (size_t)h2 * 832 + 816 + (hf & 15), s);
  }
}

__global__ __launch_bounds__(512, 2) void k_gemm1(
    const int* __restrict__ flag, const void* __restrict__ x,
    const u16* __restrict__ Bs1, const u16* __restrict__ BsKlo,
    const float* __restrict__ bcat,
    u16* __restrict__ C1, float* __restrict__ stats)
{
  __shared__ float xs[32][196];
  __shared__ float Ks[32][65];
  __shared__ float Vs[32][65];
  if (*flag) gemm1_body<true >(x, Bs1, BsKlo, bcat, C1, stats, xs, Ks, Vs);
  else       gemm1_body<false>(x, Bs1, BsKlo, bcat, C1, stats, xs, Ks, Vs);
}

// ---------------- finalize (exact sumN1 via xsum) ----------------
template<bool F32>
__device__ void finalize_body(const float* stats, const void* Pi,
                              const void* Wk, const void* bk,
                              const float* xsum, float* M, float* sn1)
{
  const int bh = blockIdx.x, bb = bh >> 2, h = bh & 3, t = threadIdx.x;
  const float* sb = stats + (size_t)bh * 832;
  float* mb = M + (size_t)bh * 784;
  const float inv6 = 1.0f / 6.0f;

  {
    int f = t >> 4, s = t & 15;
    float p = 0.f;
    for (int i = s * 12; i < s * 12 + 12; ++i)
      p += xsum[bb * 192 + i] * ldwf(Wk, i * 64 + h * 16 + f, F32);
    p += __shfl_xor(p, 1, 64);
    p += __shfl_xor(p, 2, 64);
    p += __shfl_xor(p, 4, 64);
    p += __shfl_xor(p, 8, 64);
    if (s == 0) sn1[f] = p + 4096.0f * ldwf(bk, h * 16 + f, F32);
  }
  __syncthreads();

  {
    const int f = t >> 4, c = t & 15;
    #pragma unroll
    for (int k = 0; k < 3; ++k) {
      float fkv = sb[k * 256 + f * 16 + c];
      float sk  = (k == 0) ? sn1[f] : sb[768 + k * 16 + f];
      float pi  = ldwf(Pi, h * 4 + (k + 1), F32);
      mb[k * 256 + f * 16 + c] = fkv / ((sk + 1e-8f) * 4.0f) * pi * inv6;
    }
  }
  if (t < 16) {
    float sv  = sb[816 + t];
    float pi0 = ldwf(Pi, h * 4 + 0, F32);
    mb[768 + t] = sv / (4096.0f + 1e-8f) * pi0 * inv6;
  }
}

__global__ __launch_bounds__(256) void k_finalize(
    const int* __restrict__ flag, const float* __restrict__ stats,
    const void* __restrict__ Pi, const void* __restrict__ Wk,
    const void* __restrict__ bk, const float* __restrict__ xsum,
    float* __restrict__ M)
{
  __shared__ float sn1[16];
  if (*flag) finalize_body<true >(stats, Pi, Wk, bk, xsum, M, sn1);
  else       finalize_body<false>(stats, Pi, Wk, bk, xsum, M, sn1);
}

// ---------------- mid: MFMA att + LN + MFMA FFN + LN (r17 verbatim) ---------
template<bool F32> __device__ void mid_body(
    const u16* __restrict__ C1, u16* __restrict__ R2,
    const float* __restrict__ Mall,
    const u16* __restrict__ W1f, const u16* __restrict__ W2f,
    const void* __restrict__ b1, const void* __restrict__ b2,
    const void* __restrict__ lng, const void* __restrict__ lnb,
    float (*attL)[72], u16 (*resB)[72], u16 (*hB)[136])
{
  const int tid = threadIdx.x;
  const int w = tid >> 6, l = tid & 63;
  const int lm = l & 15, lk = l >> 4;
  const int n0g = blockIdx.x * 64;
  const int b = n0g >> 12;
  const int n2_0 = n0g & 4095;
  const int h = n2_0 >> 10;
  const int qg0 = (b << 12) + ((n2_0 & 1023) << 2);
  const float* mb = Mall + (size_t)((b << 2) + h) * 784;

  short8 Bhi[2], Blo[2];
  #pragma unroll
  for (int ks = 0; ks < 2; ++ks) {
    float vh[8], vl[8];
    #pragma unroll
    for (int e = 0; e < 8; ++e) {
      int kk = ks * 32 + lk * 8 + e;
      float v = (kk < 16) ? mb[kk * 16 + lm]
              : (kk < 32) ? mb[256 + (kk - 16) * 16 + lm]
              : (kk < 48) ? mb[512 + (kk - 32) * 16 + lm] : 0.f;
      float hi = bf2f(f2bf(v));
      vh[e] = hi; vl[e] = v - hi;
    }
    Bhi[ks] = pack8(vh);
    Blo[ks] = pack8(vl);
  }
  const float c0v = mb[768 + lm];

  #pragma unroll
  for (int mt2 = 0; mt2 < 4; ++mt2) {
    const int mt = w * 4 + mt2;
    uint4 qv = *(const uint4*)(C1 + (size_t)(qg0 + mt * 16 + lm) * 128
                               + h * 16 + (lk & 1) * 8);
    float q[8] = {lo16(qv.x), hi16(qv.x), lo16(qv.y), hi16(qv.y),
                  lo16(qv.z), hi16(qv.z), lo16(qv.w), hi16(qv.w)};
    float q2[8], q3[8];
    #pragma unroll
    for (int e = 0; e < 8; ++e) { q2[e] = q[e] * q[e]; q3[e] = q2[e] * q[e]; }
    short8 a1, a2;
    if (lk < 2) { a1 = as_short8(qv); a2 = pack8(q3); }
    else        { a1 = pack8(q2);     a2 = short8{0,0,0,0,0,0,0,0}; }

    f32x4 acc = {c0v, c0v, c0v, c0v};
    acc = MFMA16(a1, Bhi[0], acc, 0, 0, 0);
    acc = MFMA16(a1, Blo[0], acc, 0, 0, 0);
    acc = MFMA16(a2, Bhi[1], acc, 0, 0, 0);
    acc = MFMA16(a2, Blo[1], acc, 0, 0, 0);

    #pragma unroll
    for (int r = 0; r < 4; ++r) {
      int qr = mt * 16 + lk * 4 + r;
      attL[qr >> 2][(qr & 3) * 16 + lm] = acc[r];
    }
  }

  const float gj = ldwf(lng, l, F32), bj = ldwf(lnb, l, F32);
  #pragma unroll 4
  for (int rr = 0; rr < 16; ++rr) {
    int r = w * 16 + rr;
    float proj = bf2f(C1[(size_t)(n0g + r) * 128 + 64 + l]);
    float y = proj + attL[r][l];
    resB[r][l] = f2bf(ln64(y, gj, bj));
  }

  short8 a0 = *(const short8*)&resB[w * 16 + lm][lk * 8];
  short8 a1f = *(const short8*)&resB[w * 16 + lm][32 + lk * 8];
  f32x4 hacc[8];
  #pragma unroll
  for (int nt = 0; nt < 8; ++nt) {
    float bv = ldwf(b1, nt * 16 + lm, F32);
    f32x4 a = {bv, bv, bv, bv};
    hacc[nt] = a;
  }
  #pragma unroll
  for (int nt = 0; nt < 8; ++nt) {
    short8 w1a = ld_frag8(W1f + (size_t)((0 * 8 + nt) * 64 + l) * 8);
    short8 w1b = ld_frag8(W1f + (size_t)((1 * 8 + nt) * 64 + l) * 8);
    hacc[nt] = MFMA16(a0, w1a, hacc[nt], 0, 0, 0);
    hacc[nt] = MFMA16(a1f, w1b, hacc[nt], 0, 0, 0);
  }
  #pragma unroll
  for (int nt = 0; nt < 8; ++nt)
    #pragma unroll
    for (int r = 0; r < 4; ++r) {
      int row = w * 16 + lk * 4 + r;
      hB[row][nt * 16 + lm] = f2bf(fmaxf(hacc[nt][r], 0.f));
    }

  short8 ha[4];
  #pragma unroll
  for (int ks = 0; ks < 4; ++ks)
    ha[ks] = *(const short8*)&hB[w * 16 + lm][ks * 32 + lk * 8];
  f32x4 oacc[4];
  #pragma unroll
  for (int nt = 0; nt < 4; ++nt) {
    float bv = ldwf(b2, nt * 16 + lm, F32);
    f32x4 a = {bv, bv, bv, bv};
    oacc[nt] = a;
  }
  #pragma unroll
  for (int ks = 0; ks < 4; ++ks)
    #pragma unroll
    for (int nt = 0; nt < 4; ++nt) {
      short8 w2v = ld_frag8(W2f + (size_t)((ks * 4 + nt) * 64 + l) * 8);
      oacc[nt] = MFMA16(ha[ks], w2v, oacc[nt], 0, 0, 0);
    }

  float gcol[4], bcol[4];
  #pragma unroll
  for (int nt = 0; nt < 4; ++nt) {
    gcol[nt] = ldwf(lng, nt * 16 + lm, F32);
    bcol[nt] = ldwf(lnb, nt * 16 + lm, F32);
  }
  #pragma unroll
  for (int r = 0; r < 4; ++r) {
    int row = w * 16 + lk * 4 + r;
    float y[4];
    float s = 0.f, sq = 0.f;
    #pragma unroll
    for (int nt = 0; nt < 4; ++nt) {
      y[nt] = oacc[nt][r] + bf2f(resB[row][nt * 16 + lm]);
      s += y[nt];
      sq = fmaf(y[nt], y[nt], sq);
    }
    #pragma unroll
    for (int off = 8; off > 0; off >>= 1) {
      s  += __shfl_xor(s, off, 64);
      sq += __shfl_xor(sq, off, 64);
    }
    float mu = s * 0.015625f;
    float var = sq * 0.015625f - mu * mu;
    float rs = rsqrtf(var + 1e-5f);
    #pragma unroll
    for (int nt = 0; nt < 4; ++nt) {
      float r2v = (y[nt] - mu) * rs * gcol[nt] + bcol[nt];
      R2[(size_t)(n0g + row) * 64 + nt * 16 + lm] = f2bf(r2v);
    }
  }
}

__global__ __launch_bounds__(256, 2) void k_mid(
    const int* __restrict__ flag, const u16* __restrict__ C1,
    u16* __restrict__ R2, const float* __restrict__ Mall,
    const u16* __restrict__ W1f, const u16* __restrict__ W2f,
    const void* __restrict__ b1, const void* __restrict__ b2,
    const void* __restrict__ lng, const void* __restrict__ lnb)
{
  __shared__ float attL[64][72];
  __shared__ u16 resB[64][72];
  __shared__ u16 hB[64][136];
  if (*flag) mid_body<true >(C1, R2, Mall, W1f, W2f, b1, b2, lng, lnb, attL, resB, hB);
  else       mid_body<false>(C1, R2, Mall, W1f, W2f, b1, b2, lng, lnb, attL, resB, hB);
}

// ---------------- GEMM2: out = [res2|x] @ [Wout;Wp] + bout (direct-x) -------
template<bool F32>
__device__ void gemm2_body(const void* __restrict__ x,
                           const u16* __restrict__ R2,
                           const u16* __restrict__ Bs2,
                           const void* __restrict__ bout,
                           void* __restrict__ out)
{
  const int l = threadIdx.x & 63;
  const int w = threadIdx.x >> 6;
  const int mbase = blockIdx.x * 64;
  const int lm = l & 15, lk = l >> 4;

  short8 bf[8][3];
  #pragma unroll
  for (int ks = 0; ks < 8; ++ks)
    #pragma unroll
    for (int nt = 0; nt < 3; ++nt)
      bf[ks][nt] = ld_frag8(Bs2 + (size_t)((ks * 12 + w * 3 + nt) * 64 + l) * 8);

  float bias[3];
  #pragma unroll
  for (int nt = 0; nt < 3; ++nt) bias[nt] = ldwf(bout, w * 48 + nt * 16 + lm, F32);

  for (int mt = 0; mt < 4; ++mt) {
    const int row = mbase + mt * 16 + lm;
    short8 af[8];
    {
      const u16* rp = R2 + (size_t)row * 64 + lk * 8;
      af[0] = ld_frag8(rp);
      af[1] = ld_frag8(rp + 32);
    }
    if constexpr (F32) {
      const float* xp = (const float*)x + (size_t)row * 192 + lk * 8;
      #pragma unroll
      for (int ks = 2; ks < 8; ++ks) {
        float4 va = *(const float4*)(xp + (ks - 2) * 32);
        float4 vb = *(const float4*)(xp + (ks - 2) * 32 + 4);
        af[ks] = packf4(va, vb);
      }
    } else {
      const u16* xp = (const u16*)x + (size_t)row * 192 + lk * 8;
      #pragma unroll
      for (int ks = 2; ks < 8; ++ks) af[ks] = ld_frag8(xp + (ks - 2) * 32);
    }

    f32x4 acc[3];
    #pragma unroll
    for (int nt = 0; nt < 3; ++nt) {
      f32x4 a = {bias[nt], bias[nt], bias[nt], bias[nt]};
      acc[nt] = a;
    }
    #pragma unroll
    for (int ks = 0; ks < 8; ++ks)
      #pragma unroll
      for (int nt = 0; nt < 3; ++nt)
        acc[nt] = MFMA16(af[ks], bf[ks][nt], acc[nt], 0, 0, 0);
    const int r0 = mbase + mt * 16 + lk * 4;
    const int c0 = w * 48 + lm;
    if constexpr (F32) {
      float* op = (float*)out;
      #pragma unroll
      for (int nt = 0; nt < 3; ++nt)
        #pragma unroll
        for (int r = 0; r < 4; ++r)
          op[(size_t)(r0 + r) * IND + c0 + nt * 16] = acc[nt][r];
    } else {
      u16* op = (u16*)out;
      #pragma unroll
      for (int nt = 0; nt < 3; ++nt)
        #pragma unroll
        for (int r = 0; r < 4; ++r)
          op[(size_t)(r0 + r) * IND + c0 + nt * 16] = f2bf(acc[nt][r]);
    }
  }
}

__global__ __launch_bounds__(256, 2) void k_gemm2(
    const int* __restrict__ flag, const void* __restrict__ x,
    const u16* __restrict__ R2, const u16* __restrict__ Bs2,
    const void* __restrict__ bout, void* __restrict__ out)
{
  if (*flag) gemm2_body<true >(x, R2, Bs2, bout, out);
  else       gemm2_body<false>(x, R2, Bs2, bout, out);
}

extern "C" void kernel_launch(void* const* d_in, const int* in_sizes, int n_in,
                              void* d_out, int out_size, void* d_ws, size_t ws_size,
                              hipStream_t stream)
{
  const void* x   = d_in[0];
  const void* Wq  = d_in[1];
  const void* bq  = d_in[2];
  const void* Wk  = d_in[3];
  const void* bk  = d_in[4];
  const void* Wv  = d_in[5];
  const void* bv  = d_in[6];
  const void* Win = d_in[7];
  const void* Wout= d_in[8];
  const void* bout= d_in[9];
  const void* W1  = d_in[10];
  const void* b1  = d_in[11];
  const void* W2  = d_in[12];
  const void* b2  = d_in[13];
  const void* lng = d_in[14];
  const void* lnb = d_in[15];
  const void* Wp  = d_in[16];
  const void* Pi  = d_in[17];

  // Layout identical to r17 (xb slot retained, now unused).
  u16* xb    = (u16*)d_ws;                  // 12,582,912 (unused)
  u16* C1    = xb + (size_t)12582912;       // 8,388,608  (Q | proj)
  u16* R2    = C1 + (size_t)8388608;        // 4,194,304  (res2)
  u16* Bs1   = R2 + (size_t)4194304;        // 49,152
  u16* BsKlo = Bs1 + 49152;                 // 12,288
  u16* Bs2   = BsKlo + 12288;               // 49,152
  u16* W1f   = Bs2 + 49152;                 // 8,192
  u16* W2f   = W1f + 8192;                  // 8,192
  float* bcat  = (float*)(W2f + 8192);      // 256
  float* stats = bcat + 256;                // 53,248
  float* xsum  = stats + 53248;             // 3,072
  float* Mc    = xsum + 3072;               // 50,176
  int*   flag  = (int*)(Mc + 50176);

  k_detect<<<1, 64, 0, stream>>>((const u32*)x, flag);
  hipMemsetAsync(stats, 0, (size_t)(53248 + 3072) * sizeof(float), stream);

  k_prepw<<<497, 256, 0, stream>>>(flag, Wq, Wk, Wv, Win, Wout, Wp, W1, W2,
                                   bq, bk, bv, Bs1, BsKlo, Bs2, W1f, W2f, bcat);
  k_xsum<<<256, 192, 0, stream>>>(flag, x, xsum);
  k_gemm1<<<2048, 512, 0, stream>>>(flag, x, Bs1, BsKlo, bcat, C1, stats);
  k_finalize<<<64, 256, 0, stream>>>(flag, stats, Pi, Wk, bk, xsum, Mc);
  k_mid<<<1024, 256, 0, stream>>>(flag, C1, R2, Mc, W1f, W2f, b1, b2, lng, lnb);
  k_gemm2<<<1024, 256, 0, stream>>>(flag, x, R2, Bs2, bout, d_out);
}